// Round 8
// baseline (79.083 us; speedup 1.0000x reference)
//
#include <hip/hip_runtime.h>
#include <hip/hip_bf16.h>

// Problem constants (fixed by setup_inputs)
#define B_ROWS 16384
#define DDIM   1024
#define CCLS   1000
#define CPAD   1024   // classes padded to 1024 (pad rows zeroed -> acc 0 -> masked)
#define GN     4      // grid-N slices (CPAD / 256)
#define NKT    16     // K-tiles (1024 / 64)

typedef __attribute__((ext_vector_type(8))) short  short8;  // 8 bf16 (4 VGPRs)
typedef __attribute__((ext_vector_type(4))) float  f32x4;   // MFMA accumulator

#define FENCE asm volatile("" ::: "memory")   // compiler fence, no HW wait

// fp32 -> bf16 round-to-nearest-even
static __device__ __forceinline__ unsigned short f2bf(float f) {
    unsigned int u = __float_as_uint(f);
    unsigned int r = 0x7fffu + ((u >> 16) & 1u);
    return (unsigned short)((u + r) >> 16);
}

// async global->LDS DMA, 16 B/lane; lds dest is WAVE-UNIFORM base (HW adds lane*16)
static __device__ __forceinline__ void gl_lds16(const unsigned short* g, unsigned short* l) {
    __builtin_amdgcn_global_load_lds(
        (const __attribute__((address_space(1))) void*)g,
        (__attribute__((address_space(3))) void*)l, 16, 0, 0);
}

// ---------------------------------------------------------------------------
// Kernel 1: prep — H -> bf16 Hb + rowscale = log2(e)/||h||; P -> Pb (padded).
//   H blocks: 16 rows each, wave owns 4 rows CONCURRENTLY (16 loads in flight
//   per wave -> latency-bound fix: 2x in-flight bytes vs round-6).
// ---------------------------------------------------------------------------
__global__ __launch_bounds__(256) void prep(
        const float* __restrict__ H, const float* __restrict__ P,
        unsigned short* __restrict__ Hb, unsigned short* __restrict__ Pb,
        float* __restrict__ rowscale) {
    const int bid = blockIdx.x;
    const int tid = threadIdx.x;
    const int w   = tid >> 6;
    const int l   = tid & 63;
    if (bid < 1024) {
        const int row0 = bid * 16 + w * 4;
        float4 v[4][4];
        #pragma unroll
        for (int r = 0; r < 4; ++r)
            #pragma unroll
            for (int c = 0; c < 4; ++c)
                v[r][c] = *reinterpret_cast<const float4*>(
                    H + (size_t)(row0 + r) * DDIM + c * 256 + l * 4);
        float ss[4];
        #pragma unroll
        for (int r = 0; r < 4; ++r) {
            unsigned short* dst = Hb + (size_t)(row0 + r) * DDIM;
            ss[r] = 0.f;
            #pragma unroll
            for (int c = 0; c < 4; ++c) {
                const float4 q = v[r][c];
                ss[r] += q.x*q.x + q.y*q.y + q.z*q.z + q.w*q.w;
                ushort4 o = {f2bf(q.x), f2bf(q.y), f2bf(q.z), f2bf(q.w)};
                *reinterpret_cast<ushort4*>(dst + c * 256 + l * 4) = o;
            }
        }
        #pragma unroll
        for (int mask = 1; mask < 64; mask <<= 1)
            #pragma unroll
            for (int r = 0; r < 4; ++r)       // 4 independent chains interleave
                ss[r] += __shfl_xor(ss[r], mask);
        if (l == 0) {
            #pragma unroll
            for (int r = 0; r < 4; ++r)
                rowscale[row0 + r] = 1.4426950408889634f * rsqrtf(ss[r]);
        }
    } else {
        const int pb = bid - 1024;   // 0..31 -> rows [pb*32, +32) of Pb
        #pragma unroll 4
        for (int c = 0; c < 32; ++c) {
            const int base = (pb * 8192 + c * 256 + tid) * 4;
            const int row  = base >> 10;
            ushort4 o;
            if (row < CCLS) {
                const float4 q = *reinterpret_cast<const float4*>(P + base);
                o.x = f2bf(q.x); o.y = f2bf(q.y); o.z = f2bf(q.z); o.w = f2bf(q.w);
            } else {
                o.x = o.y = o.z = o.w = 0;
            }
            *reinterpret_cast<ushort4*>(Pb + base) = o;
        }
    }
}

// ---------------------------------------------------------------------------
// Kernel 2: 256x256-tile GEMM, BK=64, 8-phase with ONE-PHASE-AHEAD ds_read
// prefetch. No explicit lgkm waits: compiler inserts exact counted lgkmcnt
// (frag reads are register deps of the consuming MFMA). Counted vmcnt(6) per
// K-tile gates the double-buffer swap. XOR-swizzled LDS both-sides.
//   grid = 64(M) x 4(N) = 256 blocks (1/CU), 512 threads = 8 waves (2M x 4N);
//   wave (wm,wn) owns 128x64 output: acc[8][4] (AGPR), a[4][2]+b[4][2] frags.
// ---------------------------------------------------------------------------
__global__ __launch_bounds__(512, 2) void gemm_ce(
        const unsigned short* __restrict__ Hb,
        const unsigned short* __restrict__ Pb,
        const int* __restrict__ labels,
        const float* __restrict__ rowscale,
        float* __restrict__ psum,
        float* __restrict__ plab) {
    __shared__ unsigned short Alds[2][256 * 64];   // 32 KiB per buf
    __shared__ unsigned short Blds[2][256 * 64];   // total 128 KiB

    // Bijective XCD swizzle (nwg=256 % 8 == 0)
    const int orig = blockIdx.x;
    const int wg   = (orig & 7) * 32 + (orig >> 3);
    const int bm   = wg >> 2;    // 0..63
    const int bn   = wg & 3;     // 0..3

    const int tid = threadIdx.x;
    const int w   = tid >> 6;    // wave 0..7
    const int l   = tid & 63;
    const int lo  = l & 15;
    const int hi  = l >> 4;
    const int wm  = w >> 2;      // 0..1
    const int wn  = w & 3;       // 0..3

    const size_t arow0 = (size_t)bm * 256;
    const size_t brow0 = (size_t)bn * 256;

    // Staging: one 64x64 quarter (8 KiB) per gl_lds issue; wave w covers rows
    // [q*64 + w*8, +8), lane l -> row +(l>>3), 16B chunk (l&7). LDS dest is
    // linear; SOURCE col inverse-swizzled: LDS[r][c'] = G[r][c' ^ (r&7)].
    const int srow = l >> 3;
    const int scol = ((l & 7) ^ srow) * 8;   // bf16 elems

#define STAGE_A(buf_, t_, q_) gl_lds16(                                         \
        Hb + (arow0 + (q_) * 64 + w * 8 + srow) * DDIM + (t_) * 64 + scol,      \
        &Alds[buf_][((q_) * 64 + w * 8) * 64])
#define STAGE_B(buf_, t_, q_) gl_lds16(                                         \
        Pb + (brow0 + (q_) * 64 + w * 8 + srow) * DDIM + (t_) * 64 + scol,      \
        &Blds[buf_][((q_) * 64 + w * 8) * 64])

    f32x4 acc[8][4];
    #pragma unroll
    for (int m = 0; m < 8; ++m)
        #pragma unroll
        for (int n = 0; n < 4; ++n)
            acc[m][n] = (f32x4){0.f, 0.f, 0.f, 0.f};

    const int swz   = (lo & 7) << 4;          // read-side XOR (bytes)
    const int colk[2] = { (hi << 4) ^ swz, (64 | (hi << 4)) ^ swz };

    short8 a[4][2];   // current A-half frags (role toggles: a0 ph0-1, a1 ph2-3)
    short8 b[4][2];   // b[0..1]=b01, b[2..3]=b23

    // 4 ds_read_b128: A-half mh, k-half kk -> a[mi][kk]
#define LDA_KK(buf_, mh_, kk_) do { _Pragma("unroll")                           \
    for (int mi_ = 0; mi_ < 4; ++mi_) {                                         \
        const int r_ = (wm * 128 + (mh_) * 64 + mi_ * 16 + lo) * 128;           \
        a[mi_][kk_] = *reinterpret_cast<const short8*>(                         \
            (const char*)&Alds[buf_][0] + r_ + colk[kk_]);                      \
    } } while (0)
    // 4 ds_read_b128: B-pair nh -> b[nh*2+ni][kk]
#define LDB_(buf_, nh_) do { _Pragma("unroll")                                  \
    for (int ni_ = 0; ni_ < 2; ++ni_) {                                         \
        const int r_ = (wn * 64 + ((nh_) * 2 + ni_) * 16 + lo) * 128;           \
        b[(nh_)*2+ni_][0] = *reinterpret_cast<const short8*>(                   \
            (const char*)&Blds[buf_][0] + r_ + colk[0]);                        \
        b[(nh_)*2+ni_][1] = *reinterpret_cast<const short8*>(                   \
            (const char*)&Blds[buf_][0] + r_ + colk[1]);                        \
    } } while (0)
#define MFMA_Q(mh_, nh_) do {                                                   \
    __builtin_amdgcn_s_setprio(1);                                              \
    _Pragma("unroll")                                                           \
    for (int kk_ = 0; kk_ < 2; ++kk_) { _Pragma("unroll")                       \
    for (int ni_ = 0; ni_ < 2; ++ni_) { _Pragma("unroll")                       \
    for (int mi_ = 0; mi_ < 4; ++mi_) {                                         \
        acc[(mh_)*4+mi_][(nh_)*2+ni_] = __builtin_amdgcn_mfma_f32_16x16x32_bf16(\
            a[mi_][kk_], b[(nh_)*2+ni_][kk_], acc[(mh_)*4+mi_][(nh_)*2+ni_],    \
            0, 0, 0);                                                           \
    } } }                                                                       \
    __builtin_amdgcn_s_setprio(0);                                              \
} while (0)
#define BAR do { FENCE; __builtin_amdgcn_s_barrier(); FENCE; } while (0)

// Region ledger (read-issue -> consume -> staged-over, all program-ordered):
//  a0(bufp): issued prev-ph3 post-bar; consumed ph0/ph1 MFMA; Aq0/Aq2 staged ph1
//  b01(bufp): issued prev-ph3 post-bar; consumed ph0/ph2;     Bq0/Bq1 staged ph2
//  b23(bufp): issued ph0;               consumed ph1/ph3;     Bq2/Bq3 staged ph3
//  a1(bufp): kk0 issued ph1-post, kk1 ph2-pre; consumed ph2/ph3; Aq1/Aq3 staged
//            at ph0 of NEXT tile (after this tile's final barrier)
//  ph3-post reads of buf^1 (next tile) come only after vmcnt(6)+barrier.
#define TILE_ITER(p_, t_) do {                                                  \
    /* PH0: MFMA(0,0) [a0,b01] */                                               \
    LDB_(p_, 1);                                     /* b23 prefetch */         \
    if ((t_) + 1 < NKT) { STAGE_A((p_) ^ 1, (t_) + 1, 1);                       \
                          STAGE_A((p_) ^ 1, (t_) + 1, 3); }                     \
    BAR;                                                                        \
    MFMA_Q(0, 0);                                                               \
    BAR;                                                                        \
    /* PH1: MFMA(0,1) [a0,b23] */                                               \
    if ((t_) + 2 < NKT) { STAGE_A(p_, (t_) + 2, 0); STAGE_A(p_, (t_) + 2, 2); } \
    BAR;                                                                        \
    MFMA_Q(0, 1);                                                               \
    LDA_KK(p_, 1, 0);                                /* a1-kk0 (a0 dead) */     \
    BAR;                                                                        \
    /* PH2: MFMA(1,0) [a1,b01] */                                               \
    LDA_KK(p_, 1, 1);                                /* a1-kk1 */               \
    if ((t_) + 2 < NKT) { STAGE_B(p_, (t_) + 2, 0); STAGE_B(p_, (t_) + 2, 1); } \
    BAR;                                                                        \
    MFMA_Q(1, 0);                                                               \
    BAR;                                                                        \
    /* PH3: MFMA(1,1) [a1,b23] */                                               \
    if ((t_) + 2 < NKT) { STAGE_B(p_, (t_) + 2, 2); STAGE_B(p_, (t_) + 2, 3);   \
        asm volatile("s_waitcnt vmcnt(6)" ::: "memory");                        \
    } else if ((t_) + 1 < NKT) {                                                \
        asm volatile("s_waitcnt vmcnt(0)" ::: "memory");                        \
    }                                                                           \
    BAR;                                                                        \
    MFMA_Q(1, 1);                                                               \
    if ((t_) + 1 < NKT) {                            /* next-tile a0,b01 */     \
        LDA_KK((p_) ^ 1, 0, 0); LDA_KK((p_) ^ 1, 0, 1); LDB_((p_) ^ 1, 0);      \
    }                                                                           \
    BAR;                                                                        \
} while (0)

    // Prologue: tile0 full (8) + tile1 {Aq0,Aq2,Bq0-3} (6); tile1's Aq1,Aq3
    // land at tile0-ph0. vmcnt(6) completes tile0's 8; then first frag reads.
    #pragma unroll
    for (int q = 0; q < 4; ++q) { STAGE_A(0, 0, q); STAGE_B(0, 0, q); }
    STAGE_A(1, 1, 0); STAGE_A(1, 1, 2);
    #pragma unroll
    for (int q = 0; q < 4; ++q) STAGE_B(1, 1, q);
    asm volatile("s_waitcnt vmcnt(6)" ::: "memory");
    BAR;
    LDA_KK(0, 0, 0); LDA_KK(0, 0, 1); LDB_(0, 0);    // tile0 a0, b01

    #pragma unroll 1
    for (int kt2 = 0; kt2 < NKT / 2; ++kt2) {
        const int t0 = 2 * kt2;
        TILE_ITER(0, t0);
        TILE_ITER(1, t0 + 1);
    }
#undef TILE_ITER
#undef BAR
#undef MFMA_Q
#undef LDB_
#undef LDA_KK
#undef STAGE_B
#undef STAGE_A

    // ---- Fused epilogue (per-m to bound VGPR): logits -> exp2 sums + label.
    //      C/D: class c = bn*256 + wn*64 + n*16 + lo ; row = wm*128 + m*16 + hi*4 + j
    float* red = reinterpret_cast<float*>(&Alds[0][0]);   // [256 rows][4 wn][2]
    #pragma unroll
    for (int m = 0; m < 8; ++m) {
        const int rloc = wm * 128 + m * 16 + hi * 4;
        float rs4[4], s4[4], lb2[4];
        int   lb4[4];
        #pragma unroll
        for (int j = 0; j < 4; ++j) {
            const size_t grow = arow0 + rloc + j;
            rs4[j] = rowscale[grow];   // log2(e)/||h||  (tau = 1)
            lb4[j] = labels[grow];
            s4[j]  = 0.f;
            lb2[j] = -1e30f;
        }
        #pragma unroll
        for (int n = 0; n < 4; ++n) {
            const int c = (int)brow0 + wn * 64 + n * 16 + lo;
            const float pen = (c < CCLS) ? 0.f : -1e30f;
            #pragma unroll
            for (int j = 0; j < 4; ++j) {
                const float lg = fmaf(acc[m][n][j], rs4[j], pen);
                lb2[j] = (c == lb4[j]) ? lg : lb2[j];
                s4[j] += exp2f(lg);
            }
        }
        #pragma unroll
        for (int j = 0; j < 4; ++j) {
            #pragma unroll
            for (int mask = 1; mask <= 8; mask <<= 1) {
                s4[j]  += __shfl_xor(s4[j], mask);
                lb2[j]  = fmaxf(lb2[j], __shfl_xor(lb2[j], mask));
            }
            if (lo == 0) {
                const int r = rloc + j;
                red[(r * 4 + wn) * 2 + 0] = s4[j];
                red[(r * 4 + wn) * 2 + 1] = lb2[j];
            }
        }
    }
    __syncthreads();
    if (tid < 256) {
        float st = 0.f, lt = -1e30f;
        #pragma unroll
        for (int q = 0; q < 4; ++q) {
            st += red[(tid * 4 + q) * 2 + 0];
            lt  = fmaxf(lt, red[(tid * 4 + q) * 2 + 1]);
        }
        const size_t grow = arow0 + tid;
        psum[grow * GN + bn] = st;
        plab[grow * GN + bn] = lt;
    }
}

// ---------------------------------------------------------------------------
// Kernel 3: single-block final reduction (float4 partial loads), mean loss.
// ---------------------------------------------------------------------------
__global__ __launch_bounds__(1024) void reduce_all(
        const float* __restrict__ psum, const float* __restrict__ plab,
        float* __restrict__ out) {
    const int tid = threadIdx.x;   // 1024 threads, 16 waves
    float loss = 0.f;
    #pragma unroll 4
    for (int i = 0; i < B_ROWS / 1024; ++i) {
        const int row = i * 1024 + tid;
        const float4 ps = *reinterpret_cast<const float4*>(psum + (size_t)row * GN);
        const float4 pl = *reinterpret_cast<const float4*>(plab + (size_t)row * GN);
        const float st = (ps.x + ps.y) + (ps.z + ps.w);
        const float lt = fmaxf(fmaxf(pl.x, pl.y), fmaxf(pl.z, pl.w));
        loss += 0.6931471805599453f * (log2f(st) - lt);
    }
    #pragma unroll
    for (int mask = 1; mask < 64; mask <<= 1)
        loss += __shfl_xor(loss, mask);
    __shared__ float wsum[16];
    if ((tid & 63) == 0) wsum[tid >> 6] = loss;
    __syncthreads();
    if (tid < 64) {
        float v = (tid < 16) ? wsum[tid] : 0.f;
        #pragma unroll
        for (int mask = 1; mask < 16; mask <<= 1)
            v += __shfl_xor(v, mask);
        if (tid == 0) out[0] = v * (1.0f / 16384.0f);
    }
}

extern "C" void kernel_launch(void* const* d_in, const int* in_sizes, int n_in,
                              void* d_out, int out_size, void* d_ws, size_t ws_size,
                              hipStream_t stream) {
    const float* H      = (const float*)d_in[0];   // [16384, 1024] fp32
    const float* P      = (const float*)d_in[1];   // [1000, 1024] fp32
    const int*   labels = (const int*)d_in[2];     // [16384] int32
    float* out = (float*)d_out;

    // ws layout (~34.6 MiB): Hb 32M | Pb 2M | rowscale 64K | psum 256K | plab 256K
    char* wp = (char*)d_ws;
    unsigned short* Hb = (unsigned short*)wp;   wp += (size_t)B_ROWS * DDIM * 2;
    unsigned short* Pb = (unsigned short*)wp;   wp += (size_t)CPAD * DDIM * 2;
    float* rowscale    = (float*)wp;            wp += (size_t)B_ROWS * 4;
    float* psum        = (float*)wp;            wp += (size_t)B_ROWS * GN * 4;
    float* plab        = (float*)wp;

    prep<<<1056, 256, 0, stream>>>(H, P, Hb, Pb, rowscale);
    gemm_ce<<<(B_ROWS / 256) * GN, 512, 0, stream>>>(Hb, Pb, labels, rowscale, psum, plab);
    reduce_all<<<1, 1024, 0, stream>>>(psum, plab, out);
}

// Round 9
// 78.702 us; speedup vs baseline: 1.0048x; 1.0048x over previous
//
#include <hip/hip_runtime.h>
#include <hip/hip_bf16.h>

// Problem constants (fixed by setup_inputs)
#define B_ROWS 16384
#define DDIM   1024
#define CCLS   1000
#define CPAD   1024   // classes padded to 1024 (pad rows zeroed -> acc 0 -> masked)
#define GN     4      // grid-N slices (CPAD / 256)
#define NKT    16     // K-tiles (1024 / 64)

typedef __attribute__((ext_vector_type(8))) short  short8;  // 8 bf16 (4 VGPRs)
typedef __attribute__((ext_vector_type(4))) float  f32x4;   // MFMA accumulator

#define FENCE asm volatile("" ::: "memory")   // compiler fence, no HW wait

// fp32 -> bf16 round-to-nearest-even
static __device__ __forceinline__ unsigned short f2bf(float f) {
    unsigned int u = __float_as_uint(f);
    unsigned int r = 0x7fffu + ((u >> 16) & 1u);
    return (unsigned short)((u + r) >> 16);
}

// async global->LDS DMA, 16 B/lane; lds dest is WAVE-UNIFORM base (HW adds lane*16)
static __device__ __forceinline__ void gl_lds16(const unsigned short* g, unsigned short* l) {
    __builtin_amdgcn_global_load_lds(
        (const __attribute__((address_space(1))) void*)g,
        (__attribute__((address_space(3))) void*)l, 16, 0, 0);
}

// ---------------------------------------------------------------------------
// Kernel 1: prep — H -> bf16 Hb + rowscale = log2(e)/||h||; P -> Pb (padded).
//   H blocks: 16 rows each, wave owns 4 rows CONCURRENTLY (16 loads in flight
//   per wave -> latency-bound fix: 2x in-flight bytes vs round-6).
// ---------------------------------------------------------------------------
__global__ __launch_bounds__(256) void prep(
        const float* __restrict__ H, const float* __restrict__ P,
        unsigned short* __restrict__ Hb, unsigned short* __restrict__ Pb,
        float* __restrict__ rowscale) {
    const int bid = blockIdx.x;
    const int tid = threadIdx.x;
    const int w   = tid >> 6;
    const int l   = tid & 63;
    if (bid < 1024) {
        const int row0 = bid * 16 + w * 4;
        float4 v[4][4];
        #pragma unroll
        for (int r = 0; r < 4; ++r)
            #pragma unroll
            for (int c = 0; c < 4; ++c)
                v[r][c] = *reinterpret_cast<const float4*>(
                    H + (size_t)(row0 + r) * DDIM + c * 256 + l * 4);
        float ss[4];
        #pragma unroll
        for (int r = 0; r < 4; ++r) {
            unsigned short* dst = Hb + (size_t)(row0 + r) * DDIM;
            ss[r] = 0.f;
            #pragma unroll
            for (int c = 0; c < 4; ++c) {
                const float4 q = v[r][c];
                ss[r] += q.x*q.x + q.y*q.y + q.z*q.z + q.w*q.w;
                ushort4 o = {f2bf(q.x), f2bf(q.y), f2bf(q.z), f2bf(q.w)};
                *reinterpret_cast<ushort4*>(dst + c * 256 + l * 4) = o;
            }
        }
        #pragma unroll
        for (int mask = 1; mask < 64; mask <<= 1)
            #pragma unroll
            for (int r = 0; r < 4; ++r)       // 4 independent chains interleave
                ss[r] += __shfl_xor(ss[r], mask);
        if (l == 0) {
            #pragma unroll
            for (int r = 0; r < 4; ++r)
                rowscale[row0 + r] = 1.4426950408889634f * rsqrtf(ss[r]);
        }
    } else {
        const int pb = bid - 1024;   // 0..31 -> rows [pb*32, +32) of Pb
        #pragma unroll 4
        for (int c = 0; c < 32; ++c) {
            const int base = (pb * 8192 + c * 256 + tid) * 4;
            const int row  = base >> 10;
            ushort4 o;
            if (row < CCLS) {
                const float4 q = *reinterpret_cast<const float4*>(P + base);
                o.x = f2bf(q.x); o.y = f2bf(q.y); o.z = f2bf(q.z); o.w = f2bf(q.w);
            } else {
                o.x = o.y = o.z = o.w = 0;
            }
            *reinterpret_cast<ushort4*>(Pb + base) = o;
        }
    }
}

// ---------------------------------------------------------------------------
// Kernel 2: 256x256-tile GEMM, BK=64, 8-phase with ONE-PHASE-AHEAD ds_read
// prefetch. No explicit lgkm waits: compiler inserts exact counted lgkmcnt
// (frag reads are register deps of the consuming MFMA). Counted vmcnt(6) per
// K-tile gates the double-buffer swap. XOR-swizzled LDS both-sides.
//   grid = 64(M) x 4(N) = 256 blocks (1/CU), 512 threads = 8 waves (2M x 4N);
//   wave (wm,wn) owns 128x64 output: acc[8][4] (AGPR), a[4][2]+b[4][2] frags.
// ---------------------------------------------------------------------------
__global__ __launch_bounds__(512, 2) void gemm_ce(
        const unsigned short* __restrict__ Hb,
        const unsigned short* __restrict__ Pb,
        const int* __restrict__ labels,
        const float* __restrict__ rowscale,
        float* __restrict__ psum,
        float* __restrict__ plab) {
    __shared__ unsigned short Alds[2][256 * 64];   // 32 KiB per buf
    __shared__ unsigned short Blds[2][256 * 64];   // total 128 KiB

    // Bijective XCD swizzle (nwg=256 % 8 == 0)
    const int orig = blockIdx.x;
    const int wg   = (orig & 7) * 32 + (orig >> 3);
    const int bm   = wg >> 2;    // 0..63
    const int bn   = wg & 3;     // 0..3

    const int tid = threadIdx.x;
    const int w   = tid >> 6;    // wave 0..7
    const int l   = tid & 63;
    const int lo  = l & 15;
    const int hi  = l >> 4;
    const int wm  = w >> 2;      // 0..1
    const int wn  = w & 3;       // 0..3

    const size_t arow0 = (size_t)bm * 256;
    const size_t brow0 = (size_t)bn * 256;

    // Staging: one 64x64 quarter (8 KiB) per gl_lds issue; wave w covers rows
    // [q*64 + w*8, +8), lane l -> row +(l>>3), 16B chunk (l&7). LDS dest is
    // linear; SOURCE col inverse-swizzled: LDS[r][c'] = G[r][c' ^ (r&7)].
    const int srow = l >> 3;
    const int scol = ((l & 7) ^ srow) * 8;   // bf16 elems

#define STAGE_A(buf_, t_, q_) gl_lds16(                                         \
        Hb + (arow0 + (q_) * 64 + w * 8 + srow) * DDIM + (t_) * 64 + scol,      \
        &Alds[buf_][((q_) * 64 + w * 8) * 64])
#define STAGE_B(buf_, t_, q_) gl_lds16(                                         \
        Pb + (brow0 + (q_) * 64 + w * 8 + srow) * DDIM + (t_) * 64 + scol,      \
        &Blds[buf_][((q_) * 64 + w * 8) * 64])

    f32x4 acc[8][4];
    #pragma unroll
    for (int m = 0; m < 8; ++m)
        #pragma unroll
        for (int n = 0; n < 4; ++n)
            acc[m][n] = (f32x4){0.f, 0.f, 0.f, 0.f};

    const int swz   = (lo & 7) << 4;          // read-side XOR (bytes)
    const int colk[2] = { (hi << 4) ^ swz, (64 | (hi << 4)) ^ swz };

    short8 a[4][2];   // current A-half frags (role toggles: a0 ph0-1, a1 ph2-3)
    short8 b[4][2];   // b[0..1]=b01, b[2..3]=b23

    // 4 ds_read_b128: A-half mh, k-half kk -> a[mi][kk]
#define LDA_KK(buf_, mh_, kk_) do { _Pragma("unroll")                           \
    for (int mi_ = 0; mi_ < 4; ++mi_) {                                         \
        const int r_ = (wm * 128 + (mh_) * 64 + mi_ * 16 + lo) * 128;           \
        a[mi_][kk_] = *reinterpret_cast<const short8*>(                         \
            (const char*)&Alds[buf_][0] + r_ + colk[kk_]);                      \
    } } while (0)
    // 4 ds_read_b128: B-pair nh -> b[nh*2+ni][kk]
#define LDB_(buf_, nh_) do { _Pragma("unroll")                                  \
    for (int ni_ = 0; ni_ < 2; ++ni_) {                                         \
        const int r_ = (wn * 64 + ((nh_) * 2 + ni_) * 16 + lo) * 128;           \
        b[(nh_)*2+ni_][0] = *reinterpret_cast<const short8*>(                   \
            (const char*)&Blds[buf_][0] + r_ + colk[0]);                        \
        b[(nh_)*2+ni_][1] = *reinterpret_cast<const short8*>(                   \
            (const char*)&Blds[buf_][0] + r_ + colk[1]);                        \
    } } while (0)
#define MFMA_Q(mh_, nh_) do {                                                   \
    __builtin_amdgcn_s_setprio(1);                                              \
    _Pragma("unroll")                                                           \
    for (int kk_ = 0; kk_ < 2; ++kk_) { _Pragma("unroll")                       \
    for (int ni_ = 0; ni_ < 2; ++ni_) { _Pragma("unroll")                       \
    for (int mi_ = 0; mi_ < 4; ++mi_) {                                         \
        acc[(mh_)*4+mi_][(nh_)*2+ni_] = __builtin_amdgcn_mfma_f32_16x16x32_bf16(\
            a[mi_][kk_], b[(nh_)*2+ni_][kk_], acc[(mh_)*4+mi_][(nh_)*2+ni_],    \
            0, 0, 0);                                                           \
    } } }                                                                       \
    __builtin_amdgcn_s_setprio(0);                                              \
} while (0)
#define BAR do { FENCE; __builtin_amdgcn_s_barrier(); FENCE; } while (0)

// Region ledger (read-issue -> consume -> staged-over, all program-ordered):
//  a0(bufp): issued prev-ph3 post-bar; consumed ph0/ph1 MFMA; Aq0/Aq2 staged ph1
//  b01(bufp): issued prev-ph3 post-bar; consumed ph0/ph2;     Bq0/Bq1 staged ph2
//  b23(bufp): issued ph0;               consumed ph1/ph3;     Bq2/Bq3 staged ph3
//  a1(bufp): kk0 issued ph1-post, kk1 ph2-pre; consumed ph2/ph3; Aq1/Aq3 staged
//            at ph0 of NEXT tile (after this tile's final barrier)
//  ph3-post reads of buf^1 (next tile) come only after vmcnt(6)+barrier.
#define TILE_ITER(p_, t_) do {                                                  \
    /* PH0: MFMA(0,0) [a0,b01] */                                               \
    LDB_(p_, 1);                                     /* b23 prefetch */         \
    if ((t_) + 1 < NKT) { STAGE_A((p_) ^ 1, (t_) + 1, 1);                       \
                          STAGE_A((p_) ^ 1, (t_) + 1, 3); }                     \
    BAR;                                                                        \
    MFMA_Q(0, 0);                                                               \
    BAR;                                                                        \
    /* PH1: MFMA(0,1) [a0,b23] */                                               \
    if ((t_) + 2 < NKT) { STAGE_A(p_, (t_) + 2, 0); STAGE_A(p_, (t_) + 2, 2); } \
    BAR;                                                                        \
    MFMA_Q(0, 1);                                                               \
    LDA_KK(p_, 1, 0);                                /* a1-kk0 (a0 dead) */     \
    BAR;                                                                        \
    /* PH2: MFMA(1,0) [a1,b01] */                                               \
    LDA_KK(p_, 1, 1);                                /* a1-kk1 */               \
    if ((t_) + 2 < NKT) { STAGE_B(p_, (t_) + 2, 0); STAGE_B(p_, (t_) + 2, 1); } \
    BAR;                                                                        \
    MFMA_Q(1, 0);                                                               \
    BAR;                                                                        \
    /* PH3: MFMA(1,1) [a1,b23] */                                               \
    if ((t_) + 2 < NKT) { STAGE_B(p_, (t_) + 2, 2); STAGE_B(p_, (t_) + 2, 3);   \
        asm volatile("s_waitcnt vmcnt(6)" ::: "memory");                        \
    } else if ((t_) + 1 < NKT) {                                                \
        asm volatile("s_waitcnt vmcnt(0)" ::: "memory");                        \
    }                                                                           \
    BAR;                                                                        \
    MFMA_Q(1, 1);                                                               \
    if ((t_) + 1 < NKT) {                            /* next-tile a0,b01 */     \
        LDA_KK((p_) ^ 1, 0, 0); LDA_KK((p_) ^ 1, 0, 1); LDB_((p_) ^ 1, 0);      \
    }                                                                           \
    BAR;                                                                        \
} while (0)

    // Prologue: tile0 full (8) + tile1 {Aq0,Aq2,Bq0-3} (6); tile1's Aq1,Aq3
    // land at tile0-ph0. vmcnt(6) completes tile0's 8; then first frag reads.
    #pragma unroll
    for (int q = 0; q < 4; ++q) { STAGE_A(0, 0, q); STAGE_B(0, 0, q); }
    STAGE_A(1, 1, 0); STAGE_A(1, 1, 2);
    #pragma unroll
    for (int q = 0; q < 4; ++q) STAGE_B(1, 1, q);
    asm volatile("s_waitcnt vmcnt(6)" ::: "memory");
    BAR;
    LDA_KK(0, 0, 0); LDA_KK(0, 0, 1); LDB_(0, 0);    // tile0 a0, b01

    #pragma unroll 1
    for (int kt2 = 0; kt2 < NKT / 2; ++kt2) {
        const int t0 = 2 * kt2;
        TILE_ITER(0, t0);
        TILE_ITER(1, t0 + 1);
    }
#undef TILE_ITER
#undef BAR
#undef MFMA_Q
#undef LDB_
#undef LDA_KK
#undef STAGE_B
#undef STAGE_A

    // ---- Fused epilogue (per-m to bound VGPR): logits -> exp2 sums + label.
    //      C/D: class c = bn*256 + wn*64 + n*16 + lo ; row = wm*128 + m*16 + hi*4 + j
    float* red = reinterpret_cast<float*>(&Alds[0][0]);   // [256 rows][4 wn][2]
    #pragma unroll
    for (int m = 0; m < 8; ++m) {
        const int rloc = wm * 128 + m * 16 + hi * 4;
        float rs4[4], s4[4], lb2[4];
        int   lb4[4];
        #pragma unroll
        for (int j = 0; j < 4; ++j) {
            const size_t grow = arow0 + rloc + j;
            rs4[j] = rowscale[grow];   // log2(e)/||h||  (tau = 1)
            lb4[j] = labels[grow];
            s4[j]  = 0.f;
            lb2[j] = -1e30f;
        }
        #pragma unroll
        for (int n = 0; n < 4; ++n) {
            const int c = (int)brow0 + wn * 64 + n * 16 + lo;
            const float pen = (c < CCLS) ? 0.f : -1e30f;
            #pragma unroll
            for (int j = 0; j < 4; ++j) {
                const float lg = fmaf(acc[m][n][j], rs4[j], pen);
                lb2[j] = (c == lb4[j]) ? lg : lb2[j];
                s4[j] += exp2f(lg);
            }
        }
        #pragma unroll
        for (int j = 0; j < 4; ++j) {
            #pragma unroll
            for (int mask = 1; mask <= 8; mask <<= 1) {
                s4[j]  += __shfl_xor(s4[j], mask);
                lb2[j]  = fmaxf(lb2[j], __shfl_xor(lb2[j], mask));
            }
            if (lo == 0) {
                const int r = rloc + j;
                red[(r * 4 + wn) * 2 + 0] = s4[j];
                red[(r * 4 + wn) * 2 + 1] = lb2[j];
            }
        }
    }
    __syncthreads();
    if (tid < 256) {
        float st = 0.f, lt = -1e30f;
        #pragma unroll
        for (int q = 0; q < 4; ++q) {
            st += red[(tid * 4 + q) * 2 + 0];
            lt  = fmaxf(lt, red[(tid * 4 + q) * 2 + 1]);
        }
        const size_t grow = arow0 + tid;
        psum[grow * GN + bn] = st;
        plab[grow * GN + bn] = lt;
    }
}

// ---------------------------------------------------------------------------
// Kernel 3: single-block final reduction (float4 partial loads), mean loss.
// ---------------------------------------------------------------------------
__global__ __launch_bounds__(1024) void reduce_all(
        const float* __restrict__ psum, const float* __restrict__ plab,
        float* __restrict__ out) {
    const int tid = threadIdx.x;   // 1024 threads, 16 waves
    float loss = 0.f;
    #pragma unroll 4
    for (int i = 0; i < B_ROWS / 1024; ++i) {
        const int row = i * 1024 + tid;
        const float4 ps = *reinterpret_cast<const float4*>(psum + (size_t)row * GN);
        const float4 pl = *reinterpret_cast<const float4*>(plab + (size_t)row * GN);
        const float st = (ps.x + ps.y) + (ps.z + ps.w);
        const float lt = fmaxf(fmaxf(pl.x, pl.y), fmaxf(pl.z, pl.w));
        loss += 0.6931471805599453f * (log2f(st) - lt);
    }
    #pragma unroll
    for (int mask = 1; mask < 64; mask <<= 1)
        loss += __shfl_xor(loss, mask);
    __shared__ float wsum[16];
    if ((tid & 63) == 0) wsum[tid >> 6] = loss;
    __syncthreads();
    if (tid < 64) {
        float v = (tid < 16) ? wsum[tid] : 0.f;
        #pragma unroll
        for (int mask = 1; mask < 16; mask <<= 1)
            v += __shfl_xor(v, mask);
        if (tid == 0) out[0] = v * (1.0f / 16384.0f);
    }
}

extern "C" void kernel_launch(void* const* d_in, const int* in_sizes, int n_in,
                              void* d_out, int out_size, void* d_ws, size_t ws_size,
                              hipStream_t stream) {
    const float* H      = (const float*)d_in[0];   // [16384, 1024] fp32
    const float* P      = (const float*)d_in[1];   // [1000, 1024] fp32
    const int*   labels = (const int*)d_in[2];     // [16384] int32
    float* out = (float*)d_out;

    // ws layout (~34.6 MiB): Hb 32M | Pb 2M | rowscale 64K | psum 256K | plab 256K
    char* wp = (char*)d_ws;
    unsigned short* Hb = (unsigned short*)wp;   wp += (size_t)B_ROWS * DDIM * 2;
    unsigned short* Pb = (unsigned short*)wp;   wp += (size_t)CPAD * DDIM * 2;
    float* rowscale    = (float*)wp;            wp += (size_t)B_ROWS * 4;
    float* psum        = (float*)wp;            wp += (size_t)B_ROWS * GN * 4;
    float* plab        = (float*)wp;

    prep<<<1056, 256, 0, stream>>>(H, P, Hb, Pb, rowscale);
    gemm_ce<<<(B_ROWS / 256) * GN, 512, 0, stream>>>(Hb, Pb, labels, rowscale, psum, plab);
    reduce_all<<<1, 1024, 0, stream>>>(psum, plab, out);
}